// Round 6
// baseline (111.398 us; speedup 1.0000x reference)
//
#include <hip/hip_runtime.h>

// Haar DWT2D forward: (8,32,512,512) f32 -> (8,128,257,257) f32
// out[b, k*32+c, i, jo] uses input rows {2i-1, 2i}, cols {2jo-1, 2jo},
// reflect-1 padding (-1 -> 1, 512 -> 510).
//
// r6: r5's pure-register misaligned-float4 structure, but 16 output rows per
// block (4 groups of 4) with software prefetch: group g+1's loads issue
// before group g's compute/stores. No LDS, no barriers. Fewer, longer
// read/write streams per block for DRAM locality and write-combining.

constexpr int H_IN  = 512;
constexpr int W_IN  = 512;
constexpr int H_OUT = 257;
constexpr int W_OUT = 257;
constexpr int PLANE_OUT = H_OUT * W_OUT;   // 66049
constexpr int PLANE_IN  = H_IN * W_IN;     // 262144

typedef float f4v __attribute__((ext_vector_type(4), aligned(4)));
typedef float f2v __attribute__((ext_vector_type(2), aligned(4)));

struct Grp {
    f4v   vA0, vA1, vB0, vB1;
    float tA0, tA1, tB0, tB1;
    int   iA, iB;
    bool  okA, okB;
};

__global__ __launch_bounds__(256)
void dwt2d_haar_r6(const float* __restrict__ x,
                   const float* __restrict__ filt,
                   float* __restrict__ out) {
    const int t  = threadIdx.x;
    const int j  = t & 127;           // output col-pair index
    const int s  = t >> 7;            // row set 0/1
    const int bc = blockIdx.y;        // b*32 + c
    const int i0 = blockIdx.x * 16;   // first output row of this block

    const float* xp   = x + bc * PLANE_IN;
    const int    cb   = (j == 0) ? 0 : (4 * j - 1);  // misaligned col base
    const bool   tail = (j == 127);

    auto load_grp = [&](int g) -> Grp {
        Grp G;
        G.iA  = i0 + 4 * g + s;
        G.iB  = G.iA + 2;
        G.okA = (G.iA < H_OUT);
        G.okB = (G.iB < H_OUT);
        const int iAc = G.okA ? G.iA : (H_OUT - 1);
        const int iBc = G.okB ? G.iB : (H_OUT - 1);
        int rA0 = 2 * iAc - 1; if (rA0 < 0)     rA0 = 1;
        int rA1 = 2 * iAc;     if (rA1 >= H_IN) rA1 = H_IN - 2;
        int rB0 = 2 * iBc - 1;                       // iB >= 2 always
        int rB1 = 2 * iBc;     if (rB1 >= H_IN) rB1 = H_IN - 2;
        G.tA0 = G.tA1 = G.tB0 = G.tB1 = 0.f;
        if (tail) {   // col 511 for the j0=256 output tail
            G.tA0 = xp[rA0 * W_IN + 511]; G.tA1 = xp[rA1 * W_IN + 511];
            G.tB0 = xp[rB0 * W_IN + 511]; G.tB1 = xp[rB1 * W_IN + 511];
        }
        G.vA0 = *reinterpret_cast<const f4v*>(xp + rA0 * W_IN + cb);
        G.vA1 = *reinterpret_cast<const f4v*>(xp + rA1 * W_IN + cb);
        G.vB0 = *reinterpret_cast<const f4v*>(xp + rB0 * W_IN + cb);
        G.vB1 = *reinterpret_cast<const f4v*>(xp + rB1 * W_IN + cb);
        return G;
    };

    float F[16];
#pragma unroll
    for (int k = 0; k < 16; ++k) F[k] = filt[k];

    const int bb = bc >> 5, cc = bc & 31;
    const int pbase = (bb * 128 + cc) * PLANE_OUT;

    auto emit_row = [&](int i, const f4v& v0, const f4v& v1,
                        float t0, float t1, bool ok) {
        if (!ok) return;
        // even out col 2j: window cols {4j-1, 4j}; j==0 -> {reflect 1, 0}
        float a0 = j ? v0.x : v0.y,  b0 = j ? v0.y : v0.x;
        float a1 = j ? v1.x : v1.y,  b1 = j ? v1.y : v1.x;
        // odd out col 2j+1: window cols {4j+1, 4j+2}
        float c0 = j ? v0.z : v0.y,  d0 = j ? v0.w : v0.z;
        float c1 = j ? v1.z : v1.y,  d1 = j ? v1.w : v1.z;
        const int rbase = pbase + i * W_OUT;
#pragma unroll
        for (int k = 0; k < 4; ++k) {
            float oe = F[4*k]*a0 + F[4*k+1]*b0 + F[4*k+2]*a1 + F[4*k+3]*b1;
            float oo = F[4*k]*c0 + F[4*k+1]*d0 + F[4*k+2]*c1 + F[4*k+3]*d1;
            f2v o; o.x = oe; o.y = oo;
            __builtin_nontemporal_store(
                o, reinterpret_cast<f2v*>(&out[rbase + k * 32 * PLANE_OUT + 2 * j]));
            if (tail) {   // out col 256: window cols {511, 512 -> reflect 510}
                float ot = F[4*k]*t0 + F[4*k+1]*v0.w + F[4*k+2]*t1 + F[4*k+3]*v1.w;
                __builtin_nontemporal_store(
                    ot, &out[rbase + k * 32 * PLANE_OUT + 256]);
            }
        }
    };

    auto emit_grp = [&](const Grp& G) {
        emit_row(G.iA, G.vA0, G.vA1, G.tA0, G.tA1, G.okA);
        emit_row(G.iB, G.vB0, G.vB1, G.tB0, G.tB1, G.okB);
    };

    // software pipeline: next group's loads issue before current's compute
    Grp A = load_grp(0);
    Grp B = load_grp(1);
    emit_grp(A);
    A = load_grp(2);
    emit_grp(B);
    B = load_grp(3);
    emit_grp(A);
    emit_grp(B);
}

extern "C" void kernel_launch(void* const* d_in, const int* in_sizes, int n_in,
                              void* d_out, int out_size, void* d_ws, size_t ws_size,
                              hipStream_t stream) {
    const float* x    = (const float*)d_in[0];
    const float* filt = (const float*)d_in[1];
    float*       out  = (float*)d_out;

    dim3 grid((H_OUT + 15) / 16, 256);   // 17 row-groups x 256 planes
    dwt2d_haar_r6<<<grid, 256, 0, stream>>>(x, filt, out);
}

// Round 7
// 110.239 us; speedup vs baseline: 1.0105x; 1.0105x over previous
//
#include <hip/hip_runtime.h>

// Haar DWT2D forward: (8,32,512,512) f32 -> (8,128,257,257) f32
// out[b, k*32+c, i, jo] uses input rows {2i-1, 2i}, cols {2jo-1, 2jo},
// reflect-1 padding (-1 -> 1, 512 -> 510).
//
// r7 = r5 (small blocks, pure-register, misaligned float4 loads, loads fully
// precede stores in every wave) but with REGULAR stores (not nontemporal):
// output rows are 1028 B so every row straddles cache lines; letting L2 keep
// dirty lines merges row-boundary partials from the 4 consecutive rows each
// block writes (and from concurrently-resident neighbor blocks).

constexpr int H_IN  = 512;
constexpr int W_IN  = 512;
constexpr int H_OUT = 257;
constexpr int W_OUT = 257;
constexpr int PLANE_OUT = H_OUT * W_OUT;   // 66049
constexpr int PLANE_IN  = H_IN * W_IN;     // 262144

typedef float f4v __attribute__((ext_vector_type(4), aligned(4)));
typedef float f2v __attribute__((ext_vector_type(2), aligned(4)));

__global__ __launch_bounds__(256)
void dwt2d_haar_r7(const float* __restrict__ x,
                   const float* __restrict__ filt,
                   float* __restrict__ out) {
    const int t  = threadIdx.x;
    const int j  = t & 127;          // output col-pair index
    const int s  = t >> 7;           // row set 0/1
    const int bc = blockIdx.y;       // b*32 + c
    const int i0 = blockIdx.x * 4;   // first output row of this block

    const int  iA = i0 + s;
    const int  iB = iA + 2;
    const bool vA = (iA < H_OUT);
    const bool vB = (iB < H_OUT);
    const int  iAc = vA ? iA : (H_OUT - 1);   // clamped for safe loads
    const int  iBc = vB ? iB : (H_OUT - 1);

    const float* xp = x + bc * PLANE_IN;
    const int  cb   = (j == 0) ? 0 : (4 * j - 1);  // misaligned col base
    const bool tail = (j == 127);

    int rA0 = 2 * iAc - 1; if (rA0 < 0)     rA0 = 1;
    int rA1 = 2 * iAc;     if (rA1 >= H_IN) rA1 = H_IN - 2;
    int rB0 = 2 * iBc - 1;
    int rB1 = 2 * iBc;     if (rB1 >= H_IN) rB1 = H_IN - 2;

    // tail lanes need col 511 of each input row (independent, issued first)
    float tA0 = 0.f, tA1 = 0.f, tB0 = 0.f, tB1 = 0.f;
    if (tail) {
        tA0 = xp[rA0 * W_IN + 511]; tA1 = xp[rA1 * W_IN + 511];
        tB0 = xp[rB0 * W_IN + 511]; tB1 = xp[rB1 * W_IN + 511];
    }

    // 4 independent (possibly misaligned) 16B loads, all in flight at once
    f4v vA0 = *reinterpret_cast<const f4v*>(xp + rA0 * W_IN + cb);
    f4v vA1 = *reinterpret_cast<const f4v*>(xp + rA1 * W_IN + cb);
    f4v vB0 = *reinterpret_cast<const f4v*>(xp + rB0 * W_IN + cb);
    f4v vB1 = *reinterpret_cast<const f4v*>(xp + rB1 * W_IN + cb);

    float F[16];
#pragma unroll
    for (int k = 0; k < 16; ++k) F[k] = filt[k];

    const int bb = bc >> 5, cc = bc & 31;
    const int pbase = (bb * 128 + cc) * PLANE_OUT;

    auto emit = [&](int i, const f4v& v0, const f4v& v1,
                    float t0, float t1, bool valid) {
        if (!valid) return;
        // even out col 2j: window cols {4j-1, 4j}; j==0 -> {reflect 1, 0}
        float a0 = j ? v0.x : v0.y,  b0 = j ? v0.y : v0.x;
        float a1 = j ? v1.x : v1.y,  b1 = j ? v1.y : v1.x;
        // odd out col 2j+1: window cols {4j+1, 4j+2}
        float c0 = j ? v0.z : v0.y,  d0 = j ? v0.w : v0.z;
        float c1 = j ? v1.z : v1.y,  d1 = j ? v1.w : v1.z;
        const int rbase = pbase + i * W_OUT;
#pragma unroll
        for (int k = 0; k < 4; ++k) {
            float oe = F[4*k]*a0 + F[4*k+1]*b0 + F[4*k+2]*a1 + F[4*k+3]*b1;
            float oo = F[4*k]*c0 + F[4*k+1]*d0 + F[4*k+2]*c1 + F[4*k+3]*d1;
            f2v o; o.x = oe; o.y = oo;
            *reinterpret_cast<f2v*>(&out[rbase + k * 32 * PLANE_OUT + 2 * j]) = o;
            if (tail) {   // out col 256: window cols {511, 512 -> reflect 510}
                out[rbase + k * 32 * PLANE_OUT + 256] =
                    F[4*k]*t0 + F[4*k+1]*v0.w + F[4*k+2]*t1 + F[4*k+3]*v1.w;
            }
        }
    };

    emit(iA, vA0, vA1, tA0, tA1, vA);
    emit(iB, vB0, vB1, tB0, tB1, vB);
}

extern "C" void kernel_launch(void* const* d_in, const int* in_sizes, int n_in,
                              void* d_out, int out_size, void* d_ws, size_t ws_size,
                              hipStream_t stream) {
    const float* x    = (const float*)d_in[0];
    const float* filt = (const float*)d_in[1];
    float*       out  = (float*)d_out;

    dim3 grid((H_OUT + 3) / 4, 256);   // 65 row-groups x 256 planes
    dwt2d_haar_r7<<<grid, 256, 0, stream>>>(x, filt, out);
}